// Round 6
// baseline (30.466 us; speedup 1.0000x reference)
//
#include <hip/hip_runtime.h>
#include <math.h>

// Problem constants: Q=4, N=64, H=256, C=1, L=1024
#define QQ 4
#define NN 64
#define HH 256

// ws float layout:
//   [0, 524288)            pole tables: 128 float4 per (q,h)  (2 MB)
//   [524288, 525312)       per-(q,h) sum of B*C               (4 KB)
//   [1048576, 2097152)     x buffer  [Q*H][1024]              (4 MB)
#define TAB_F4_PER_QH 128
#define SUMS_OFF      524288
#define XBUF_OFF      1048576

__device__ __forceinline__ float vcos(float rev) { return __builtin_amdgcn_cosf(rev); }
__device__ __forceinline__ float vsin(float rev) { return __builtin_amdgcn_sinf(rev); }

// ---------- Kernel 0: pole table precompute ----------
__global__ __launch_bounds__(256)
void tssm_prep(const float* __restrict__ diagonal,      // [Q][N]
               const float* __restrict__ lowrank,       // [Q][N]
               const float* __restrict__ input_matrix,  // [Q][N]
               const float* __restrict__ output_matrix, // [Q][1][H][N]
               float* __restrict__ ws)
{
    const int gt = blockIdx.x * 256 + threadIdx.x;   // 0..65535
    const int qh = gt >> 6;
    const int n  = gt & 63;
    const int q  = qh >> 8;

    float a  = __expf(diagonal[q * NN + n]);
    float B  = input_matrix[q * NN + n];
    float P  = lowrank[q * NN + n];
    float Cm = output_matrix[qh * NN + n];
    float w0 = B * Cm;

    float4* tab = (float4*)ws + (size_t)qh * TAB_F4_PER_QH;
    tab[2 * n]     = make_float4(a, a * a, w0, B * P);
    tab[2 * n + 1] = make_float4(P * Cm, P * P, 0.0f, 0.0f);

    float acc = w0;
    #pragma unroll
    for (int off = 32; off >= 1; off >>= 1) acc += __shfl_xor(acc, off, 64);
    if (n == 0) ws[SUMS_OFF + qh] = acc;
}

// ---------- Kernel 1: spectrum + 512-pt inverse Stockham FFT ----------
__global__ __launch_bounds__(512, 8)
void tssm_main(const float* __restrict__ timestep,  // [Q][H]
               float* __restrict__ ws)
{
    __shared__ __align__(16) float2 bufA[512];
    __shared__ __align__(16) float2 bufB[513];

    const int qh = blockIdx.x;        // 0..1023
    const int q  = qh >> 8;
    const int h  = qh & (HH - 1);
    const int t  = threadIdx.x;       // 0..511

    const float tv   = __expf(timestep[q * HH + h]);
    const float invt = __builtin_amdgcn_rcpf(tv);

    // ---------------- Phase A: bin l = t ----------------
    const float f  = (float)t * (1.0f / 1024.0f);
    const float tn = sinpif(f) * __builtin_amdgcn_rcpf(cospif(f));
    const float ze = 2.0f * tn * invt;
    const float z2 = ze * ze;

    const float4* __restrict__ tab = (const float4*)ws + (size_t)qh * TAB_F4_PER_QH;

    // Re k_j = sum w_j*a*g ; S_j = sum w_j*g ; Im k_j = -ze*S_j
    float r_0=0,r_1=0,r_2=0,r_3=0, s_0=0,s_1=0,s_2=0,s_3=0;
    #pragma unroll 8
    for (int n = 0; n < NN; ++n) {
        float4 A4 = tab[2 * n];       // (a, a2, w0, w1) — uniform -> s_load
        float4 B4 = tab[2 * n + 1];   // (w2, w3, -, -)
        float g  = __builtin_amdgcn_rcpf(A4.y + z2);
        float ag = A4.x * g;
        r_0 = fmaf(A4.z, ag, r_0); s_0 = fmaf(A4.z, g, s_0);
        r_1 = fmaf(A4.w, ag, r_1); s_1 = fmaf(A4.w, g, s_1);
        r_2 = fmaf(B4.x, ag, r_2); s_2 = fmaf(B4.x, g, s_2);
        r_3 = fmaf(B4.y, ag, r_3); s_3 = fmaf(B4.y, g, s_3);
    }
    {
        float i0 = -ze * s_0, i1 = -ze * s_1, i2 = -ze * s_2, i3 = -ze * s_3;
        float dr = 1.0f + r_3, di = i3;
        float nr = r_2 * r_1 - i2 * i1;
        float ni = r_2 * i1 + i2 * r_1;
        float invm = __builtin_amdgcn_rcpf(fmaf(dr, dr, di * di));
        float qr = (nr * dr + ni * di) * invm;
        float qi = (ni * dr - nr * di) * invm;
        float Kr = r_0 - qr, Ki = i0 - qi;
        bufB[t] = make_float2(fmaf(-tn, Ki, Kr), fmaf(tn, Kr, Ki));
    }
    if (t == 0) bufB[512] = make_float2(0.5f * tv * ws[SUMS_OFF + qh], 0.0f);
    __syncthreads();

    // ---------------- Y build (k = t) ----------------
    {
        float2 A  = bufB[t];
        float2 Bv = bufB[512 - t];
        float c1 = vcos((float)t * 0.0009765625f);   // 2*pi*t/1024
        float s1 = vsin((float)t * 0.0009765625f);
        float Dr = A.x - Bv.x, Di = A.y + Bv.y;
        float twDr = fmaf(c1, Dr, -s1 * Di);
        float twDi = fmaf(c1, Di,  s1 * Dr);
        bufA[t] = make_float2(0.5f * (A.x + Bv.x) - 0.5f * twDi,
                              0.5f * (A.y - Bv.y) + 0.5f * twDr);
    }
    __syncthreads();

    // ------------- Stages (output-centric: thread t owns output point t) ----
    #define FFT_STAGE(NS, LOG2NS, REVNS, SRC, DST)                        \
    {                                                                     \
        int rr   = t & (2 * (NS) - 1);                                    \
        int base = rr & ((NS) - 1);                                       \
        int j    = ((t >> ((LOG2NS) + 1)) << (LOG2NS)) | base;            \
        float2 u = (SRC)[j];                                              \
        float2 v = (SRC)[j + 256];                                        \
        float rev = (float)base * (REVNS);                                \
        float cw = vcos(rev), sw = vsin(rev);                             \
        float vr = fmaf(cw, v.x, -sw * v.y);                              \
        float vi = fmaf(cw, v.y,  sw * v.x);                              \
        float sg = (rr < (NS)) ? 1.0f : -1.0f;                            \
        (DST)[t] = make_float2(fmaf(sg, vr, u.x), fmaf(sg, vi, u.y));     \
        __syncthreads();                                                  \
    }

    FFT_STAGE(1,   0, 0.5f,         bufA, bufB)
    FFT_STAGE(2,   1, 0.25f,        bufB, bufA)
    FFT_STAGE(4,   2, 0.125f,       bufA, bufB)
    FFT_STAGE(8,   3, 0.0625f,      bufB, bufA)
    FFT_STAGE(16,  4, 0.03125f,     bufA, bufB)
    FFT_STAGE(32,  5, 0.015625f,    bufB, bufA)
    FFT_STAGE(64,  6, 0.0078125f,   bufA, bufB)
    FFT_STAGE(128, 7, 0.00390625f,  bufB, bufA)
    #undef FFT_STAGE

    // ---------------- Stage Ns=256 -> coalesced x-buffer store ----------------
    {
        int base = t & 255;
        float2 u = bufA[base];
        float2 v = bufA[base + 256];
        float rev = (float)base * 0.001953125f;      // base/512 revolutions
        float cw = vcos(rev), sw = vsin(rev);
        float vr = fmaf(cw, v.x, -sw * v.y);
        float vi = fmaf(cw, v.y,  sw * v.x);
        float sg = (t < 256) ? 1.0f : -1.0f;
        const float sc = 1.0f / 512.0f;
        float2* wsq = (float2*)(ws + XBUF_OFF) + ((size_t)qh << 9);
        wsq[t] = make_float2(fmaf(sg, vr, u.x) * sc, fmaf(sg, vi, u.y) * sc);
    }
}

// ---------- Kernel 2: x[q][h][s] -> out[s][q][h] ----------
__global__ __launch_bounds__(256)
void tssm_transpose(const float* __restrict__ ws, float* __restrict__ out)
{
    __shared__ float tile[64][65];
    const float* x = ws + XBUF_OFF;
    const int t  = threadIdx.x;
    const int hs = blockIdx.x;        // 0..3
    const int ss = blockIdx.y;        // 0..15
    const int q  = blockIdx.z;        // 0..3
    const int c  = t & 63;
    const int r0 = t >> 6;
    const int hbase = (q << 8) + (hs << 6);

    #pragma unroll
    for (int rr = 0; rr < 64; rr += 4) {
        int hh = hbase + rr + r0;
        tile[rr + r0][c] = x[(hh << 10) + (ss << 6) + c];
    }
    __syncthreads();
    #pragma unroll
    for (int rr = 0; rr < 64; rr += 4) {
        int s = (ss << 6) + rr + r0;
        out[(s << 10) + hbase + c] = tile[c][rr + r0];
    }
}

extern "C" void kernel_launch(void* const* d_in, const int* in_sizes, int n_in,
                              void* d_out, int out_size, void* d_ws, size_t ws_size,
                              hipStream_t stream) {
    (void)in_sizes; (void)n_in; (void)out_size; (void)ws_size;
    const float* diagonal      = (const float*)d_in[0];
    const float* lowrank       = (const float*)d_in[1];
    const float* timestep      = (const float*)d_in[2];
    const float* input_matrix  = (const float*)d_in[3];
    const float* output_matrix = (const float*)d_in[4];
    float* ws  = (float*)d_ws;
    float* out = (float*)d_out;

    hipLaunchKernelGGL(tssm_prep, dim3(256), dim3(256), 0, stream,
                       diagonal, lowrank, input_matrix, output_matrix, ws);
    hipLaunchKernelGGL(tssm_main, dim3(QQ * HH), dim3(512), 0, stream,
                       timestep, ws);
    hipLaunchKernelGGL(tssm_transpose, dim3(4, 16, 4), dim3(256), 0, stream,
                       ws, out);
}

// Round 7
// 28.049 us; speedup vs baseline: 1.0861x; 1.0861x over previous
//
#include <hip/hip_runtime.h>
#include <math.h>

// Problem constants: Q=4, N=64, H=256, C=1, L=1024
#define QQ 4
#define NN 64
#define HH 256

// ws float layout:
//   [0, 524288)        pole tables: 128 float4 per (q,h)  (2 MB)
//   [524288, 525312)   per-(q,h) sum of B*C               (4 KB)
//   [525312, 525824)   tan(pi*l/1024), l=0..511           (2 KB)
//   [1048576, 2097152) x buffer [Q*H][1024]               (4 MB)
#define TAB_F4_PER_QH 128
#define SUMS_OFF      524288
#define TAN_OFF       525312
#define XBUF_OFF      1048576

__device__ __forceinline__ float vcos(float rev) { return __builtin_amdgcn_cosf(rev); }
__device__ __forceinline__ float vsin(float rev) { return __builtin_amdgcn_sinf(rev); }

// ---------- Kernel 0: pole tables + B*C sums + tangent table ----------
__global__ __launch_bounds__(256)
void tssm_prep(const float* __restrict__ diagonal,      // [Q][N]
               const float* __restrict__ lowrank,       // [Q][N]
               const float* __restrict__ input_matrix,  // [Q][N]
               const float* __restrict__ output_matrix, // [Q][1][H][N]
               float* __restrict__ ws)
{
    const int blk = blockIdx.x;
    const int tid = threadIdx.x;

    if (blk >= 256) {               // tangent table: l = (blk-256)*256 + tid
        int l = ((blk - 256) << 8) + tid;
        float f = (float)l * (1.0f / 1024.0f);
        ws[TAN_OFF + l] = sinpif(f) * __builtin_amdgcn_rcpf(cospif(f));
        return;
    }

    const int gt = blk * 256 + tid;   // 0..65535
    const int qh = gt >> 6;
    const int n  = gt & 63;
    const int q  = qh >> 8;

    float a  = __expf(diagonal[q * NN + n]);
    float B  = input_matrix[q * NN + n];
    float P  = lowrank[q * NN + n];
    float Cm = output_matrix[qh * NN + n];
    float w0 = B * Cm;

    float4* tab = (float4*)ws + (size_t)qh * TAB_F4_PER_QH;
    tab[2 * n]     = make_float4(a, a * a, w0, B * P);
    tab[2 * n + 1] = make_float4(P * Cm, P * P, 0.0f, 0.0f);

    float acc = w0;
    #pragma unroll
    for (int off = 32; off >= 1; off >>= 1) acc += __shfl_xor(acc, off, 64);
    if (n == 0) ws[SUMS_OFF + qh] = acc;
}

// ---------- Kernel 1: spectrum + 512-pt inverse Stockham FFT ----------
// tab/sums/tanl are READ-ONLY restrict pointers; xout is the only store
// target -> uniform tab loads can be promoted to s_load (SGPR streaming).
__global__ __launch_bounds__(512, 8)
void tssm_main(const float* __restrict__ timestep,   // [Q][H]
               const float4* __restrict__ tab,       // [Q*H][128]
               const float* __restrict__ sums,       // [Q*H]
               const float* __restrict__ tanl,       // [512]
               float2* __restrict__ xout)            // [Q*H][512] float2
{
    __shared__ __align__(16) float2 bufA[512];
    __shared__ __align__(16) float2 bufB[513];

    const int qh = blockIdx.x;        // 0..1023
    const int q  = qh >> 8;
    const int h  = qh & (HH - 1);
    const int t  = threadIdx.x;       // 0..511

    const float tv   = __expf(timestep[q * HH + h]);
    const float invt = __builtin_amdgcn_rcpf(tv);

    // ---------------- Phase A: bin l = t ----------------
    const float tn = tanl[t];
    const float ze = 2.0f * tn * invt;
    const float z2 = ze * ze;

    const float4* __restrict__ tq = tab + (size_t)qh * TAB_F4_PER_QH;

    float r_0=0,r_1=0,r_2=0,r_3=0, s_0=0,s_1=0,s_2=0,s_3=0;
    #pragma unroll 8
    for (int n = 0; n < NN; ++n) {
        float4 A4 = tq[2 * n];        // (a, a2, w0, w1) — uniform -> s_load
        float4 B4 = tq[2 * n + 1];    // (w2, w3, -, -)
        float g  = __builtin_amdgcn_rcpf(A4.y + z2);
        float ag = A4.x * g;
        r_0 = fmaf(A4.z, ag, r_0); s_0 = fmaf(A4.z, g, s_0);
        r_1 = fmaf(A4.w, ag, r_1); s_1 = fmaf(A4.w, g, s_1);
        r_2 = fmaf(B4.x, ag, r_2); s_2 = fmaf(B4.x, g, s_2);
        r_3 = fmaf(B4.y, ag, r_3); s_3 = fmaf(B4.y, g, s_3);
    }
    {
        float i0 = -ze * s_0, i1 = -ze * s_1, i2 = -ze * s_2, i3 = -ze * s_3;
        float dr = 1.0f + r_3, di = i3;
        float nr = r_2 * r_1 - i2 * i1;
        float ni = r_2 * i1 + i2 * r_1;
        float invm = __builtin_amdgcn_rcpf(fmaf(dr, dr, di * di));
        float qr = (nr * dr + ni * di) * invm;
        float qi = (ni * dr - nr * di) * invm;
        float Kr = r_0 - qr, Ki = i0 - qi;
        bufB[t] = make_float2(fmaf(-tn, Ki, Kr), fmaf(tn, Kr, Ki));
    }
    if (t == 0) bufB[512] = make_float2(0.5f * tv * sums[qh], 0.0f);
    __syncthreads();

    // ---------------- Y build (k = t) ----------------
    {
        float2 A  = bufB[t];
        float2 Bv = bufB[512 - t];
        float c1 = vcos((float)t * 0.0009765625f);   // 2*pi*t/1024
        float s1 = vsin((float)t * 0.0009765625f);
        float Dr = A.x - Bv.x, Di = A.y + Bv.y;
        float twDr = fmaf(c1, Dr, -s1 * Di);
        float twDi = fmaf(c1, Di,  s1 * Dr);
        bufA[t] = make_float2(0.5f * (A.x + Bv.x) - 0.5f * twDi,
                              0.5f * (A.y - Bv.y) + 0.5f * twDr);
    }
    __syncthreads();

    // ------------- Stages (output-centric: thread t owns output point t) ----
    #define FFT_STAGE(NS, LOG2NS, REVNS, SRC, DST)                        \
    {                                                                     \
        int rr   = t & (2 * (NS) - 1);                                    \
        int base = rr & ((NS) - 1);                                       \
        int j    = ((t >> ((LOG2NS) + 1)) << (LOG2NS)) | base;            \
        float2 u = (SRC)[j];                                              \
        float2 v = (SRC)[j + 256];                                        \
        float rev = (float)base * (REVNS);                                \
        float cw = vcos(rev), sw = vsin(rev);                             \
        float vr = fmaf(cw, v.x, -sw * v.y);                              \
        float vi = fmaf(cw, v.y,  sw * v.x);                              \
        float sg = (rr < (NS)) ? 1.0f : -1.0f;                            \
        (DST)[t] = make_float2(fmaf(sg, vr, u.x), fmaf(sg, vi, u.y));     \
        __syncthreads();                                                  \
    }

    FFT_STAGE(1,   0, 0.5f,         bufA, bufB)
    FFT_STAGE(2,   1, 0.25f,        bufB, bufA)
    FFT_STAGE(4,   2, 0.125f,       bufA, bufB)
    FFT_STAGE(8,   3, 0.0625f,      bufB, bufA)
    FFT_STAGE(16,  4, 0.03125f,     bufA, bufB)
    FFT_STAGE(32,  5, 0.015625f,    bufB, bufA)
    FFT_STAGE(64,  6, 0.0078125f,   bufA, bufB)
    FFT_STAGE(128, 7, 0.00390625f,  bufB, bufA)
    #undef FFT_STAGE

    // ---------------- Stage Ns=256 -> coalesced x-buffer store ----------------
    {
        int base = t & 255;
        float2 u = bufA[base];
        float2 v = bufA[base + 256];
        float rev = (float)base * 0.001953125f;      // base/512 revolutions
        float cw = vcos(rev), sw = vsin(rev);
        float vr = fmaf(cw, v.x, -sw * v.y);
        float vi = fmaf(cw, v.y,  sw * v.x);
        float sg = (t < 256) ? 1.0f : -1.0f;
        const float sc = 1.0f / 512.0f;
        xout[((size_t)qh << 9) + t] =
            make_float2(fmaf(sg, vr, u.x) * sc, fmaf(sg, vi, u.y) * sc);
    }
}

// ---------- Kernel 2: x[q][h][s] -> out[s][q][h] ----------
__global__ __launch_bounds__(256)
void tssm_transpose(const float* __restrict__ x, float* __restrict__ out)
{
    __shared__ float tile[64][65];
    const int t  = threadIdx.x;
    const int hs = blockIdx.x;        // 0..3
    const int ss = blockIdx.y;        // 0..15
    const int q  = blockIdx.z;        // 0..3
    const int c  = t & 63;
    const int r0 = t >> 6;
    const int hbase = (q << 8) + (hs << 6);

    #pragma unroll
    for (int rr = 0; rr < 64; rr += 4) {
        int hh = hbase + rr + r0;
        tile[rr + r0][c] = x[(hh << 10) + (ss << 6) + c];
    }
    __syncthreads();
    #pragma unroll
    for (int rr = 0; rr < 64; rr += 4) {
        int s = (ss << 6) + rr + r0;
        out[(s << 10) + hbase + c] = tile[c][rr + r0];
    }
}

extern "C" void kernel_launch(void* const* d_in, const int* in_sizes, int n_in,
                              void* d_out, int out_size, void* d_ws, size_t ws_size,
                              hipStream_t stream) {
    (void)in_sizes; (void)n_in; (void)out_size; (void)ws_size;
    const float* diagonal      = (const float*)d_in[0];
    const float* lowrank       = (const float*)d_in[1];
    const float* timestep      = (const float*)d_in[2];
    const float* input_matrix  = (const float*)d_in[3];
    const float* output_matrix = (const float*)d_in[4];
    float* ws  = (float*)d_ws;
    float* out = (float*)d_out;

    const float4* tabp  = (const float4*)ws;
    const float*  sumsp = ws + SUMS_OFF;
    const float*  tanp  = ws + TAN_OFF;
    float2*       xoutp = (float2*)(ws + XBUF_OFF);
    const float*  xinp  = ws + XBUF_OFF;

    hipLaunchKernelGGL(tssm_prep, dim3(258), dim3(256), 0, stream,
                       diagonal, lowrank, input_matrix, output_matrix, ws);
    hipLaunchKernelGGL(tssm_main, dim3(QQ * HH), dim3(512), 0, stream,
                       timestep, tabp, sumsp, tanp, xoutp);
    hipLaunchKernelGGL(tssm_transpose, dim3(4, 16, 4), dim3(256), 0, stream,
                       xinp, out);
}